// Round 1
// baseline (1545.340 us; speedup 1.0000x reference)
//
#include <hip/hip_runtime.h>
#include <math.h>

#pragma clang fp contract(off)

// Per-triangle record (16 floats = 64 B):
//  [0]=bx [1]=by [2]=cx-bx [3]=cy-by     -> w0 = t2*(py-t1) - t3*(px-t0)
//  [4]=cx [5]=cy [6]=ax-cx [7]=ay-cy     -> w1 = t6*(py-t5) - t7*(px-t4)
//  [8]=ax [9]=ay [10]=bx-ax [11]=by-ay   -> w2 = t10*(py-t9) - t11*(px-t8)
//  [12]=inv_area (NaN if |area|<=1e-9 -> barycentrics NaN -> inside==false)
#define CHUNK 128

__global__ void bake_prep(const float* __restrict__ uv, const int* __restrict__ faces,
                          float* __restrict__ tris, int nTri) {
    int f = blockIdx.x * blockDim.x + threadIdx.x;
    if (f >= nTri) return;
    int i0 = faces[3 * f + 0], i1 = faces[3 * f + 1], i2 = faces[3 * f + 2];
    float ax = uv[2 * i0 + 0], ay = uv[2 * i0 + 1];
    float bx = uv[2 * i1 + 0], by = uv[2 * i1 + 1];
    float cx = uv[2 * i2 + 0], cy = uv[2 * i2 + 1];
    float area = (bx - ax) * (cy - ay) - (by - ay) * (cx - ax);
    float inv = (fabsf(area) > 1e-9f) ? (1.0f / area) : __int_as_float(0x7FC00000);
    float* t = tris + 16 * f;
    t[0] = bx; t[1] = by; t[2]  = cx - bx; t[3]  = cy - by;
    t[4] = cx; t[5] = cy; t[6]  = ax - cx; t[7]  = ay - cy;
    t[8] = ax; t[9] = ay; t[10] = bx - ax; t[11] = by - ay;
    t[12] = inv; t[13] = 0.f; t[14] = 0.f; t[15] = 0.f;
}

template <bool PREP>
__global__ __launch_bounds__(256) void bake_main(
    const float* __restrict__ tris, const float* __restrict__ uv,
    const int* __restrict__ faces, const float* __restrict__ attr,
    float* __restrict__ out, int res, int nTri) {
    constexpr int S = PREP ? 16 : 17;   // stride 17 in on-the-fly path dodges LDS write conflicts
    __shared__ float smem[CHUNK * S];

    int tx = threadIdx.x & 15, ty = threadIdx.x >> 4;
    int pxi = blockIdx.x * 16 + tx;
    int pyi = blockIdx.y * 16 + ty;
    bool inb = (pxi < res) && (pyi < res);
    float rf = (float)res;
    float px = ((float)pxi + 0.5f) / rf;   // matches xs = (arange+0.5)/res
    float py = ((float)pyi + 0.5f) / rf;

    int best = inb ? -1 : 0x7FFFFFF0;      // out-of-range threads count as "done"
    float g0 = 0.f, g1 = 0.f, g2 = 0.f;

    for (int base = 0; base < nTri; base += CHUNK) {
        int n = min(CHUNK, nTri - base);
        if (PREP) {
            const float4* src = (const float4*)(tris + (size_t)base * 16);
            float4* dst = (float4*)smem;
            int nv = n * 4;
            for (int v = threadIdx.x; v < nv; v += 256) dst[v] = src[v];
        } else {
            for (int i = threadIdx.x; i < n; i += 256) {
                int f = base + i;
                int i0 = faces[3 * f + 0], i1 = faces[3 * f + 1], i2 = faces[3 * f + 2];
                float ax = uv[2 * i0 + 0], ay = uv[2 * i0 + 1];
                float bx = uv[2 * i1 + 0], by = uv[2 * i1 + 1];
                float cx = uv[2 * i2 + 0], cy = uv[2 * i2 + 1];
                float area = (bx - ax) * (cy - ay) - (by - ay) * (cx - ax);
                float inv = (fabsf(area) > 1e-9f) ? (1.0f / area) : __int_as_float(0x7FC00000);
                float* t = smem + i * S;
                t[0] = bx; t[1] = by; t[2]  = cx - bx; t[3]  = cy - by;
                t[4] = cx; t[5] = cy; t[6]  = ax - cx; t[7]  = ay - cy;
                t[8] = ax; t[9] = ay; t[10] = bx - ax; t[11] = by - ay;
                t[12] = inv;
            }
        }
        __syncthreads();

        if (best < 0) {
            for (int i = 0; i < n; ++i) {
                const float* t = smem + i * S;
                // Exact operand order of the reference edge() in fp32, no FMA contraction.
                float w0 = t[2] * (py - t[1]) - t[3] * (px - t[0]);
                float b0 = w0 * t[12];
                if (!(b0 >= 0.0f)) continue;
                float w1 = t[6] * (py - t[5]) - t[7] * (px - t[4]);
                float b1 = w1 * t[12];
                if (!(b1 >= 0.0f)) continue;
                float w2 = t[10] * (py - t[9]) - t[11] * (px - t[8]);
                float b2 = w2 * t[12];
                if (!(b2 >= 0.0f)) continue;
                best = base + i; g0 = b0; g1 = b1; g2 = b2;
                break;                      // ascending scan -> first hit == argmax over bools
            }
        }
        if (__syncthreads_and(best >= 0)) break;   // also protects smem before next stage
    }

    if (!inb) return;
    float o0 = 0.f, o1 = 0.f, o2 = 0.f;
    if (best >= 0 && best < nTri) {
        int i0 = faces[3 * best + 0], i1 = faces[3 * best + 1], i2 = faces[3 * best + 2];
        o0 = g0 * attr[3 * i0 + 0] + g1 * attr[3 * i1 + 0] + g2 * attr[3 * i2 + 0];
        o1 = g0 * attr[3 * i0 + 1] + g1 * attr[3 * i1 + 1] + g2 * attr[3 * i2 + 1];
        o2 = g0 * attr[3 * i0 + 2] + g1 * attr[3 * i1 + 2] + g2 * attr[3 * i2 + 2];
    }
    int o = (pyi * res + pxi) * 3;
    out[o + 0] = o0; out[o + 1] = o1; out[o + 2] = o2;
}

extern "C" void kernel_launch(void* const* d_in, const int* in_sizes, int n_in,
                              void* d_out, int out_size, void* d_ws, size_t ws_size,
                              hipStream_t stream) {
    const float* attr  = (const float*)d_in[0];
    const float* uv    = (const float*)d_in[1];
    const int*   faces = (const int*)d_in[2];
    float*       out   = (float*)d_out;

    int nTri = in_sizes[2] / 3;
    // res*res*3 == out_size (bake_resolution lives in device memory; derive on host).
    int res = (int)(sqrt((double)(out_size / 3)) + 0.5);

    dim3 grid((res + 15) / 16, (res + 15) / 16);

    if (ws_size >= (size_t)nTri * 64) {
        float* tris = (float*)d_ws;
        bake_prep<<<(nTri + 255) / 256, 256, 0, stream>>>(uv, faces, tris, nTri);
        bake_main<true><<<grid, 256, 0, stream>>>(tris, uv, faces, attr, out, res, nTri);
    } else {
        bake_main<false><<<grid, 256, 0, stream>>>(nullptr, uv, faces, attr, out, res, nTri);
    }
}

// Round 2
// 1428.926 us; speedup vs baseline: 1.0815x; 1.0815x over previous
//
#include <hip/hip_runtime.h>
#include <math.h>

#pragma clang fp contract(off)

// One wave (64 lanes) per texel. Lanes test triangles base+lane in ascending
// index order; __ballot + ctz gives the FIRST inside triangle == the
// reference's argmax over booleans. Interior texels hit in ~1 iteration;
// boundary/corner texels (low per-triangle hit probability) scan deep but at
// 64 triangles/iteration instead of 1.
__global__ __launch_bounds__(256) void bake_wave(
    const float* __restrict__ uv, const int* __restrict__ faces,
    const float* __restrict__ attr, float* __restrict__ out,
    int res, int nTri)
{
    const int lane = threadIdx.x & 63;
    const int wid  = blockIdx.x * (blockDim.x >> 6) + (threadIdx.x >> 6);
    const int npix = res * res;
    if (wid >= npix) return;

    const int pyi = wid / res;
    const int pxi = wid - pyi * res;
    const float rf = (float)res;
    const float px = ((float)pxi + 0.5f) / rf;   // matches (arange+0.5)/res
    const float py = ((float)pyi + 0.5f) / rf;

    // Software-pipelined face-index prefetch (hides faces->uv dependent gather).
    int i0 = 0, i1 = 0, i2 = 0;
    if (lane < nTri) {
        i0 = faces[3 * lane + 0];
        i1 = faces[3 * lane + 1];
        i2 = faces[3 * lane + 2];
    }

    for (int base = 0; base < nTri; base += 64) {
        const int t  = base + lane;
        const int tn = t + 64;
        int n0 = 0, n1 = 0, n2 = 0;
        if (tn < nTri) {
            n0 = faces[3 * tn + 0];
            n1 = faces[3 * tn + 1];
            n2 = faces[3 * tn + 2];
        }

        bool hit = false;
        float b0 = 0.f, b1 = 0.f, b2 = 0.f;
        if (t < nTri) {
            const float ax = uv[2 * i0], ay = uv[2 * i0 + 1];
            const float bx = uv[2 * i1], by = uv[2 * i1 + 1];
            const float cx = uv[2 * i2], cy = uv[2 * i2 + 1];
            // Exact reference arithmetic (fp32, no FMA contraction, IEEE div).
            const float area = (bx - ax) * (cy - ay) - (by - ay) * (cx - ax);
            if (fabsf(area) > 1e-9f) {
                const float inv = 1.0f / area;
                const float w0 = (cx - bx) * (py - by) - (cy - by) * (px - bx);
                const float w1 = (ax - cx) * (py - cy) - (ay - cy) * (px - cx);
                const float w2 = (bx - ax) * (py - ay) - (by - ay) * (px - ax);
                b0 = w0 * inv; b1 = w1 * inv; b2 = w2 * inv;
                hit = (b0 >= 0.f) & (b1 >= 0.f) & (b2 >= 0.f);
            }
        }

        const unsigned long long m = __ballot(hit);
        if (m) {                                   // wave-uniform
            const int src = (int)__builtin_ctzll(m);  // lowest index = first hit
            b0 = __shfl(b0, src, 64);
            b1 = __shfl(b1, src, 64);
            b2 = __shfl(b2, src, 64);
            const int j0 = __shfl(i0, src, 64);
            const int j1 = __shfl(i1, src, 64);
            const int j2 = __shfl(i2, src, 64);
            if (lane == 0) {
                const int o = wid * 3;
                out[o + 0] = b0 * attr[3 * j0 + 0] + b1 * attr[3 * j1 + 0] + b2 * attr[3 * j2 + 0];
                out[o + 1] = b0 * attr[3 * j0 + 1] + b1 * attr[3 * j1 + 1] + b2 * attr[3 * j2 + 1];
                out[o + 2] = b0 * attr[3 * j0 + 2] + b1 * attr[3 * j1 + 2] + b2 * attr[3 * j2 + 2];
            }
            return;
        }
        i0 = n0; i1 = n1; i2 = n2;
    }

    if (lane == 0) {   // no triangle covers this texel
        const int o = wid * 3;
        out[o + 0] = 0.f; out[o + 1] = 0.f; out[o + 2] = 0.f;
    }
}

extern "C" void kernel_launch(void* const* d_in, const int* in_sizes, int n_in,
                              void* d_out, int out_size, void* d_ws, size_t ws_size,
                              hipStream_t stream) {
    const float* attr  = (const float*)d_in[0];
    const float* uv    = (const float*)d_in[1];
    const int*   faces = (const int*)d_in[2];
    float*       out   = (float*)d_out;

    const int nTri = in_sizes[2] / 3;
    const int res  = (int)(sqrt((double)(out_size / 3)) + 0.5);
    const int npix = res * res;

    const int wavesPerBlock = 4;                 // 256 threads
    const int nBlocks = (npix + wavesPerBlock - 1) / wavesPerBlock;
    bake_wave<<<nBlocks, 256, 0, stream>>>(uv, faces, attr, out, res, nTri);
}

// Round 3
// 419.791 us; speedup vs baseline: 3.6812x; 3.4039x over previous
//
#include <hip/hip_runtime.h>
#include <math.h>

#pragma clang fp contract(off)

// argmax over booleans == lowest triangle index containing the pixel center.
// Phase 1: per-triangle scatter over its conservative pixel bbox, exact
//          reference inside test, read-filtered atomicMin into bestTri.
// Phase 2: per-pixel resolve: recompute barycentrics for the winning triangle
//          (bit-identical reference arithmetic) and interpolate attributes.

#define ROWCHUNK 1024

__global__ __launch_bounds__(256) void scatter_min(
    const float* __restrict__ uv, const int* __restrict__ faces,
    int* __restrict__ bestTri, int res, int nTri)
{
    __shared__ float pyTab[ROWCHUNK];

    const int tri = blockIdx.x;
    if (tri >= nTri) return;

    const int i0 = faces[3 * tri + 0], i1 = faces[3 * tri + 1], i2 = faces[3 * tri + 2];
    const float ax = uv[2 * i0], ay = uv[2 * i0 + 1];
    const float bx = uv[2 * i1], by = uv[2 * i1 + 1];
    const float cx = uv[2 * i2], cy = uv[2 * i2 + 1];

    // Reference: area = (b0-a0)*(c1-a1) - (b1-a1)*(c0-a0); valid iff |area|>1e-9
    const float area = (bx - ax) * (cy - ay) - (by - ay) * (cx - ax);
    if (!(fabsf(area) > 1e-9f)) return;          // invalid -> never inside
    const float inv = 1.0f / area;

    const float rf = (float)res;
    const float bxmin = fminf(ax, fminf(bx, cx)), bxmax = fmaxf(ax, fmaxf(bx, cx));
    const float bymin = fminf(ay, fminf(by, cy)), bymax = fmaxf(ay, fmaxf(by, cy));
    // conservative pixel bbox with +-1 px slack (exact test decides membership)
    const int x0 = max(0, (int)floorf(bxmin * rf - 0.5f) - 1);
    const int x1 = min(res - 1, (int)ceilf(bxmax * rf - 0.5f) + 1);
    const int y0 = max(0, (int)floorf(bymin * rf - 0.5f) - 1);
    const int y1 = min(res - 1, (int)ceilf(bymax * rf - 0.5f) + 1);
    if (x1 < x0 || y1 < y0) return;

    // hoisted edge deltas (values identical to reference's (r-q) subterms)
    const float e0x = cx - bx, e0y = cy - by;     // w0 uses q=b, r=c
    const float e1x = ax - cx, e1y = ay - cy;     // w1 uses q=c, r=a
    const float e2x = bx - ax, e2y = by - ay;     // w2 uses q=a, r=b

    for (int rowBase = y0; rowBase <= y1; rowBase += ROWCHUNK) {
        const int nRows = min(ROWCHUNK, y1 - rowBase + 1);
        __syncthreads();                          // protect pyTab reuse
        for (int i = threadIdx.x; i < nRows; i += 256)
            pyTab[i] = ((float)(rowBase + i) + 0.5f) / rf;   // exact ref op
        __syncthreads();

        for (int colBase = x0; colBase <= x1; colBase += 256) {
            const int col = colBase + threadIdx.x;
            if (col > x1) continue;               // keep wave for syncthreads above
            const float px = ((float)col + 0.5f) / rf;       // exact ref op
            const float pxb = px - bx, pxc = px - cx, pxa = px - ax;
            for (int r = 0; r < nRows; ++r) {
                const float py = pyTab[r];        // uniform LDS broadcast
                // Exact reference operand order, fp32, no FMA contraction.
                const float w0 = e0x * (py - by) - e0y * pxb;
                const float w1 = e1x * (py - cy) - e1y * pxc;
                const float w2 = e2x * (py - ay) - e2y * pxa;
                const float b0 = w0 * inv, b1 = w1 * inv, b2 = w2 * inv;
                if ((b0 >= 0.f) & (b1 >= 0.f) & (b2 >= 0.f)) {
                    const int p = (rowBase + r) * res + col;
                    if (tri < bestTri[p]) atomicMin(&bestTri[p], tri);
                }
            }
        }
    }
}

__global__ __launch_bounds__(256) void resolve(
    const float* __restrict__ uv, const int* __restrict__ faces,
    const float* __restrict__ attr, const int* __restrict__ bestTri,
    float* __restrict__ out, int res, int nTri)
{
    const int p = blockIdx.x * 256 + threadIdx.x;
    const int npix = res * res;
    if (p >= npix) return;

    const int t = bestTri[p];
    float o0 = 0.f, o1 = 0.f, o2 = 0.f;
    if (t >= 0 && t < nTri) {
        const int pyi = p / res, pxi = p - pyi * res;
        const float rf = (float)res;
        const float px = ((float)pxi + 0.5f) / rf;
        const float py = ((float)pyi + 0.5f) / rf;
        const int i0 = faces[3 * t + 0], i1 = faces[3 * t + 1], i2 = faces[3 * t + 2];
        const float ax = uv[2 * i0], ay = uv[2 * i0 + 1];
        const float bx = uv[2 * i1], by = uv[2 * i1 + 1];
        const float cx = uv[2 * i2], cy = uv[2 * i2 + 1];
        const float area = (bx - ax) * (cy - ay) - (by - ay) * (cx - ax);
        const float inv = 1.0f / area;            // t was selected => valid
        const float w0 = (cx - bx) * (py - by) - (cy - by) * (px - bx);
        const float w1 = (ax - cx) * (py - cy) - (ay - cy) * (px - cx);
        const float w2 = (bx - ax) * (py - ay) - (by - ay) * (px - ax);
        const float b0 = w0 * inv, b1 = w1 * inv, b2 = w2 * inv;
        o0 = b0 * attr[3 * i0 + 0] + b1 * attr[3 * i1 + 0] + b2 * attr[3 * i2 + 0];
        o1 = b0 * attr[3 * i0 + 1] + b1 * attr[3 * i1 + 1] + b2 * attr[3 * i2 + 1];
        o2 = b0 * attr[3 * i0 + 2] + b1 * attr[3 * i1 + 2] + b2 * attr[3 * i2 + 2];
    }
    const int o = p * 3;
    out[o + 0] = o0; out[o + 1] = o1; out[o + 2] = o2;
}

// ---- fallback (no workspace): proven-correct wave-per-pixel scan ----
__global__ __launch_bounds__(256) void bake_wave(
    const float* __restrict__ uv, const int* __restrict__ faces,
    const float* __restrict__ attr, float* __restrict__ out,
    int res, int nTri)
{
    const int lane = threadIdx.x & 63;
    const int wid  = blockIdx.x * (blockDim.x >> 6) + (threadIdx.x >> 6);
    const int npix = res * res;
    if (wid >= npix) return;
    const int pyi = wid / res, pxi = wid - pyi * res;
    const float rf = (float)res;
    const float px = ((float)pxi + 0.5f) / rf, py = ((float)pyi + 0.5f) / rf;
    for (int base = 0; base < nTri; base += 64) {
        const int t = base + lane;
        bool hit = false; float b0 = 0, b1 = 0, b2 = 0; int i0 = 0, i1 = 0, i2 = 0;
        if (t < nTri) {
            i0 = faces[3 * t]; i1 = faces[3 * t + 1]; i2 = faces[3 * t + 2];
            const float ax = uv[2 * i0], ay = uv[2 * i0 + 1];
            const float bx = uv[2 * i1], by = uv[2 * i1 + 1];
            const float cx = uv[2 * i2], cy = uv[2 * i2 + 1];
            const float area = (bx - ax) * (cy - ay) - (by - ay) * (cx - ax);
            if (fabsf(area) > 1e-9f) {
                const float inv = 1.0f / area;
                b0 = ((cx - bx) * (py - by) - (cy - by) * (px - bx)) * inv;
                b1 = ((ax - cx) * (py - cy) - (ay - cy) * (px - cx)) * inv;
                b2 = ((bx - ax) * (py - ay) - (by - ay) * (px - ax)) * inv;
                hit = (b0 >= 0.f) & (b1 >= 0.f) & (b2 >= 0.f);
            }
        }
        const unsigned long long m = __ballot(hit);
        if (m) {
            const int src = (int)__builtin_ctzll(m);
            b0 = __shfl(b0, src, 64); b1 = __shfl(b1, src, 64); b2 = __shfl(b2, src, 64);
            const int j0 = __shfl(i0, src, 64), j1 = __shfl(i1, src, 64), j2 = __shfl(i2, src, 64);
            if (lane == 0) {
                const int o = wid * 3;
                out[o + 0] = b0 * attr[3 * j0] + b1 * attr[3 * j1] + b2 * attr[3 * j2];
                out[o + 1] = b0 * attr[3 * j0 + 1] + b1 * attr[3 * j1 + 1] + b2 * attr[3 * j2 + 1];
                out[o + 2] = b0 * attr[3 * j0 + 2] + b1 * attr[3 * j1 + 2] + b2 * attr[3 * j2 + 2];
            }
            return;
        }
    }
    if (lane == 0) { const int o = wid * 3; out[o] = 0.f; out[o + 1] = 0.f; out[o + 2] = 0.f; }
}

extern "C" void kernel_launch(void* const* d_in, const int* in_sizes, int n_in,
                              void* d_out, int out_size, void* d_ws, size_t ws_size,
                              hipStream_t stream) {
    const float* attr  = (const float*)d_in[0];
    const float* uv    = (const float*)d_in[1];
    const int*   faces = (const int*)d_in[2];
    float*       out   = (float*)d_out;

    const int nTri = in_sizes[2] / 3;
    const int res  = (int)(sqrt((double)(out_size / 3)) + 0.5);
    const int npix = res * res;

    if (ws_size >= (size_t)npix * sizeof(int)) {
        int* bestTri = (int*)d_ws;
        // 0x7F7F7F7F sentinel: > any triangle index, < INT_MAX overflow games.
        hipMemsetAsync(bestTri, 0x7F, (size_t)npix * sizeof(int), stream);
        scatter_min<<<nTri, 256, 0, stream>>>(uv, faces, bestTri, res, nTri);
        resolve<<<(npix + 255) / 256, 256, 0, stream>>>(uv, faces, attr, bestTri, out, res, nTri);
    } else {
        bake_wave<<<(npix + 3) / 4, 256, 0, stream>>>(uv, faces, attr, out, res, nTri);
    }
}

// Round 4
// 200.494 us; speedup vs baseline: 7.7077x; 2.0938x over previous
//
#include <hip/hip_runtime.h>
#include <math.h>

#pragma clang fp contract(off)

#define TILE 16
#define CHUNKTRI 8192   // LDS list capacity (uint16 per entry)

// Per-triangle record (16 dwords = 64 B):
//  [0]=bx [1]=by [2]=cx-bx [3]=cy-by
//  [4]=cx [5]=cy [6]=ax-cx [7]=ay-cy
//  [8]=ax [9]=ay [10]=bx-ax [11]=by-ay
//  [12]=inv_area  [13..15]=i0,i1,i2 (int bits)
__global__ __launch_bounds__(256) void prep(
    const float* __restrict__ uv, const int* __restrict__ faces,
    float* __restrict__ recs, float4* __restrict__ bboxes, int nTri)
{
    const int f = blockIdx.x * 256 + threadIdx.x;
    if (f >= nTri) return;
    const int i0 = faces[3 * f], i1 = faces[3 * f + 1], i2 = faces[3 * f + 2];
    const float ax = uv[2 * i0], ay = uv[2 * i0 + 1];
    const float bx = uv[2 * i1], by = uv[2 * i1 + 1];
    const float cx = uv[2 * i2], cy = uv[2 * i2 + 1];
    // Exact reference arithmetic (fp32, no contraction).
    const float area = (bx - ax) * (cy - ay) - (by - ay) * (cx - ax);
    const bool valid = fabsf(area) > 1e-9f;
    float* r = recs + 16 * f;
    r[0] = bx; r[1] = by; r[2]  = cx - bx; r[3]  = cy - by;
    r[4] = cx; r[5] = cy; r[6]  = ax - cx; r[7]  = ay - cy;
    r[8] = ax; r[9] = ay; r[10] = bx - ax; r[11] = by - ay;
    r[12] = valid ? 1.0f / area : 0.f;
    ((int*)r)[13] = i0; ((int*)r)[14] = i1; ((int*)r)[15] = i2;
    float bxmin = fminf(ax, fminf(bx, cx)), bxmax = fmaxf(ax, fmaxf(bx, cx));
    float bymin = fminf(ay, fminf(by, cy)), bymax = fmaxf(ay, fmaxf(by, cy));
    if (!valid) { bxmin = 2.f; bxmax = -2.f; }   // never overlaps any tile
    bboxes[f] = make_float4(bxmin, bymin, bxmax, bymax);
}

__global__ __launch_bounds__(256) void bake_tile(
    const float* __restrict__ recs, const float4* __restrict__ bboxes,
    const float* __restrict__ attr, float* __restrict__ out, int res, int nTri)
{
    __shared__ unsigned short list[CHUNKTRI];
    __shared__ int waveCnt[4];

    const int tx = threadIdx.x & 15, ty = threadIdx.x >> 4;
    const int pxi = blockIdx.x * TILE + tx;
    const int pyi = blockIdx.y * TILE + ty;
    const bool inb = (pxi < res) && (pyi < res);
    const float rf = (float)res;
    const float px = ((float)pxi + 0.5f) / rf;     // exact reference op
    const float py = ((float)pyi + 0.5f) / rf;

    // Tile rect covering all pixel centers, widened by ~1px (conservative).
    const float rx0 = ((float)(blockIdx.x * TILE) - 1.0f) / rf;
    const float rx1 = ((float)(blockIdx.x * TILE + TILE) + 1.0f) / rf;
    const float ry0 = ((float)(blockIdx.y * TILE) - 1.0f) / rf;
    const float ry1 = ((float)(blockIdx.y * TILE + TILE) + 1.0f) / rf;

    const int lane = threadIdx.x & 63, wv = threadIdx.x >> 6;
    bool done = !inb;

    for (int chunkBase = 0; chunkBase < nTri; chunkBase += CHUNKTRI) {
        const int chunkEnd = min(nTri, chunkBase + CHUNKTRI);

        // ---- Phase A: ordered candidate-list build (no atomics) ----
        int listLen = 0;
        for (int base = chunkBase; base < chunkEnd; base += 256) {
            const int t = base + threadIdx.x;
            bool keep = false;
            if (t < chunkEnd) {
                const float4 bb = bboxes[t];
                keep = (bb.x <= rx1) & (bb.z >= rx0) & (bb.y <= ry1) & (bb.w >= ry0);
            }
            const unsigned long long m = __ballot(keep);
            if (lane == 0) waveCnt[wv] = __popcll(m);
            __syncthreads();
            const int pre = __popcll(m & ((1ull << lane) - 1ull));
            int off = 0;
            #pragma unroll
            for (int w = 0; w < 4; ++w) if (w < wv) off += waveCnt[w];
            const int tot = waveCnt[0] + waveCnt[1] + waveCnt[2] + waveCnt[3];
            if (keep) list[listLen + off + pre] = (unsigned short)(t - chunkBase);
            __syncthreads();
            listLen += tot;
        }

        // ---- Phase B: per-pixel ordered scan, early exit at first hit ----
        if (!done) {
            for (int i = 0; i < listLen; ++i) {
                // i is uniform over the wave's active lanes -> scalarize record addr
                const int t = __builtin_amdgcn_readfirstlane(chunkBase + (int)list[i]);
                const float* r = recs + 16 * t;
                const float bx = r[0], by = r[1], e0x = r[2],  e0y = r[3];
                const float w0 = e0x * (py - by) - e0y * (px - bx);
                const float inv = r[12];
                const float b0 = w0 * inv;
                if (!(b0 >= 0.f)) continue;
                const float cx = r[4], cy = r[5], e1x = r[6],  e1y = r[7];
                const float w1 = e1x * (py - cy) - e1y * (px - cx);
                const float b1 = w1 * inv;
                if (!(b1 >= 0.f)) continue;
                const float ax = r[8], ay = r[9], e2x = r[10], e2y = r[11];
                const float w2 = e2x * (py - ay) - e2y * (px - ax);
                const float b2 = w2 * inv;
                if (!(b2 >= 0.f)) continue;
                const int i0 = ((const int*)r)[13], i1 = ((const int*)r)[14], i2 = ((const int*)r)[15];
                const int o = (pyi * res + pxi) * 3;
                out[o + 0] = b0 * attr[3 * i0 + 0] + b1 * attr[3 * i1 + 0] + b2 * attr[3 * i2 + 0];
                out[o + 1] = b0 * attr[3 * i0 + 1] + b1 * attr[3 * i1 + 1] + b2 * attr[3 * i2 + 1];
                out[o + 2] = b0 * attr[3 * i0 + 2] + b1 * attr[3 * i1 + 2] + b2 * attr[3 * i2 + 2];
                done = true;
                break;
            }
        }
        if (__syncthreads_and(done)) break;   // also protects list/waveCnt reuse
    }

    if (inb && !done) {
        const int o = (pyi * res + pxi) * 3;
        out[o + 0] = 0.f; out[o + 1] = 0.f; out[o + 2] = 0.f;
    }
}

// ---- fallback (tiny workspace): proven-correct wave-per-pixel scan ----
__global__ __launch_bounds__(256) void bake_wave(
    const float* __restrict__ uv, const int* __restrict__ faces,
    const float* __restrict__ attr, float* __restrict__ out,
    int res, int nTri)
{
    const int lane = threadIdx.x & 63;
    const int wid  = blockIdx.x * (blockDim.x >> 6) + (threadIdx.x >> 6);
    const int npix = res * res;
    if (wid >= npix) return;
    const int pyi = wid / res, pxi = wid - pyi * res;
    const float rf = (float)res;
    const float px = ((float)pxi + 0.5f) / rf, py = ((float)pyi + 0.5f) / rf;
    for (int base = 0; base < nTri; base += 64) {
        const int t = base + lane;
        bool hit = false; float b0 = 0, b1 = 0, b2 = 0; int i0 = 0, i1 = 0, i2 = 0;
        if (t < nTri) {
            i0 = faces[3 * t]; i1 = faces[3 * t + 1]; i2 = faces[3 * t + 2];
            const float ax = uv[2 * i0], ay = uv[2 * i0 + 1];
            const float bx = uv[2 * i1], by = uv[2 * i1 + 1];
            const float cx = uv[2 * i2], cy = uv[2 * i2 + 1];
            const float area = (bx - ax) * (cy - ay) - (by - ay) * (cx - ax);
            if (fabsf(area) > 1e-9f) {
                const float inv = 1.0f / area;
                b0 = ((cx - bx) * (py - by) - (cy - by) * (px - bx)) * inv;
                b1 = ((ax - cx) * (py - cy) - (ay - cy) * (px - cx)) * inv;
                b2 = ((bx - ax) * (py - ay) - (by - ay) * (px - ax)) * inv;
                hit = (b0 >= 0.f) & (b1 >= 0.f) & (b2 >= 0.f);
            }
        }
        const unsigned long long m = __ballot(hit);
        if (m) {
            const int src = (int)__builtin_ctzll(m);
            b0 = __shfl(b0, src, 64); b1 = __shfl(b1, src, 64); b2 = __shfl(b2, src, 64);
            const int j0 = __shfl(i0, src, 64), j1 = __shfl(i1, src, 64), j2 = __shfl(i2, src, 64);
            if (lane == 0) {
                const int o = wid * 3;
                out[o + 0] = b0 * attr[3 * j0] + b1 * attr[3 * j1] + b2 * attr[3 * j2];
                out[o + 1] = b0 * attr[3 * j0 + 1] + b1 * attr[3 * j1 + 1] + b2 * attr[3 * j2 + 1];
                out[o + 2] = b0 * attr[3 * j0 + 2] + b1 * attr[3 * j1 + 2] + b2 * attr[3 * j2 + 2];
            }
            return;
        }
    }
    if (lane == 0) { const int o = wid * 3; out[o] = 0.f; out[o + 1] = 0.f; out[o + 2] = 0.f; }
}

extern "C" void kernel_launch(void* const* d_in, const int* in_sizes, int n_in,
                              void* d_out, int out_size, void* d_ws, size_t ws_size,
                              hipStream_t stream) {
    const float* attr  = (const float*)d_in[0];
    const float* uv    = (const float*)d_in[1];
    const int*   faces = (const int*)d_in[2];
    float*       out   = (float*)d_out;

    const int nTri = in_sizes[2] / 3;
    const int res  = (int)(sqrt((double)(out_size / 3)) + 0.5);
    const int npix = res * res;

    const size_t recsBytes = (size_t)nTri * 64;
    const size_t bboxBytes = (size_t)nTri * 16;

    if (ws_size >= recsBytes + bboxBytes) {
        float*  recs   = (float*)d_ws;
        float4* bboxes = (float4*)((char*)d_ws + recsBytes);
        prep<<<(nTri + 255) / 256, 256, 0, stream>>>(uv, faces, recs, bboxes, nTri);
        dim3 grid((res + TILE - 1) / TILE, (res + TILE - 1) / TILE);
        bake_tile<<<grid, 256, 0, stream>>>(recs, bboxes, attr, out, res, nTri);
    } else {
        bake_wave<<<(npix + 3) / 4, 256, 0, stream>>>(uv, faces, attr, out, res, nTri);
    }
}

// Round 5
// 69.618 us; speedup vs baseline: 22.1974x; 2.8799x over previous
//
#include <hip/hip_runtime.h>
#include <math.h>

#pragma clang fp contract(off)

#define TILE 16
#define CHUNKTRI 8192   // LDS list capacity (uint16 per entry)

// Per-triangle record (16 dwords = 64 B):
//  [0]=bx [1]=by [2]=cx-bx [3]=cy-by      (edge0: q=b, e=c-b)
//  [4]=cx [5]=cy [6]=ax-cx [7]=ay-cy      (edge1: q=c, e=a-c)
//  [8]=ax [9]=ay [10]=bx-ax [11]=by-ay    (edge2: q=a, e=b-a)
//  [12]=inv_area  [13..15]=i0,i1,i2 (int bits)
__global__ __launch_bounds__(256) void prep(
    const float* __restrict__ uv, const int* __restrict__ faces,
    float* __restrict__ recs, float4* __restrict__ bboxes, int nTri)
{
    const int f = blockIdx.x * 256 + threadIdx.x;
    if (f >= nTri) return;
    const int i0 = faces[3 * f], i1 = faces[3 * f + 1], i2 = faces[3 * f + 2];
    const float ax = uv[2 * i0], ay = uv[2 * i0 + 1];
    const float bx = uv[2 * i1], by = uv[2 * i1 + 1];
    const float cx = uv[2 * i2], cy = uv[2 * i2 + 1];
    // Exact reference arithmetic (fp32, no contraction).
    const float area = (bx - ax) * (cy - ay) - (by - ay) * (cx - ax);
    const bool valid = fabsf(area) > 1e-9f;
    float* r = recs + 16 * f;
    r[0] = bx; r[1] = by; r[2]  = cx - bx; r[3]  = cy - by;
    r[4] = cx; r[5] = cy; r[6]  = ax - cx; r[7]  = ay - cy;
    r[8] = ax; r[9] = ay; r[10] = bx - ax; r[11] = by - ay;
    r[12] = valid ? 1.0f / area : 0.f;
    ((int*)r)[13] = i0; ((int*)r)[14] = i1; ((int*)r)[15] = i2;
    float bxmin = fminf(ax, fminf(bx, cx)), bxmax = fmaxf(ax, fmaxf(bx, cx));
    float bymin = fminf(ay, fminf(by, cy)), bymax = fmaxf(ay, fmaxf(by, cy));
    if (!valid) { bxmin = 2.f; bxmax = -2.f; }   // never overlaps any tile
    bboxes[f] = make_float4(bxmin, bymin, bxmax, bymax);
}

// Conservative: can s*w_edge be >= 0 anywhere in rect [rx0,rx1]x[ry0,ry1]?
// s*w = (s*ex)*(py-qy) + (-s*ey)*(px-qx), affine -> max at a corner.
__device__ __forceinline__ bool edgeMayPass(
    float qx, float qy, float ex, float ey, float s,
    float rx0, float rx1, float ry0, float ry1)
{
    const float A = s * ex;
    const float B = -s * ey;
    const float fy = A * ((A >= 0.f ? ry1 : ry0) - qy);
    const float fx = B * ((B >= 0.f ? rx1 : rx0) - qx);
    return (fy + fx) >= -1e-5f;   // margin >> fp eval error (~1e-6)
}

__global__ __launch_bounds__(256) void bake_tile(
    const float* __restrict__ recs, const float4* __restrict__ bboxes,
    const float* __restrict__ attr, float* __restrict__ out, int res, int nTri)
{
    __shared__ unsigned short list[CHUNKTRI];
    __shared__ int waveCnt[4];

    const int tx = threadIdx.x & 15, ty = threadIdx.x >> 4;
    const int pxi = blockIdx.x * TILE + tx;
    const int pyi = blockIdx.y * TILE + ty;
    const bool inb = (pxi < res) && (pyi < res);
    const float rf = (float)res;
    const float px = ((float)pxi + 0.5f) / rf;     // exact reference op
    const float py = ((float)pyi + 0.5f) / rf;

    // Rect containing all the tile's pixel centers, +-1.5px conservative slack.
    const float rx0 = ((float)(blockIdx.x * TILE) - 1.0f) / rf;
    const float rx1 = ((float)(blockIdx.x * TILE + TILE) + 1.0f) / rf;
    const float ry0 = ((float)(blockIdx.y * TILE) - 1.0f) / rf;
    const float ry1 = ((float)(blockIdx.y * TILE + TILE) + 1.0f) / rf;

    const int lane = threadIdx.x & 63, wv = threadIdx.x >> 6;

    bool hit = false;
    float g0 = 0.f, g1 = 0.f, g2 = 0.f;
    int j0 = 0, j1 = 0, j2 = 0;

    for (int chunkBase = 0; chunkBase < nTri; chunkBase += CHUNKTRI) {
        const int chunkEnd = min(nTri, chunkBase + CHUNKTRI);
        __syncthreads();   // protect list reuse across chunks

        // ---- Phase A: ordered candidate list, bbox + edge-SAT prune ----
        int listLen = 0;
        for (int base = chunkBase; base < chunkEnd; base += 256) {
            const int t = base + threadIdx.x;
            bool keep = false;
            if (t < chunkEnd) {
                const float4 bb = bboxes[t];
                keep = (bb.x <= rx1) & (bb.z >= rx0) & (bb.y <= ry1) & (bb.w >= ry0);
                if (keep) {
                    const float4* rr = (const float4*)(recs + 16 * t);
                    const float4 e0 = rr[0], e1 = rr[1], e2 = rr[2];
                    const float inv = ((const float*)rr)[12];
                    const float s = (inv >= 0.f) ? 1.f : -1.f;
                    keep = (inv != 0.f)
                        && edgeMayPass(e0.x, e0.y, e0.z, e0.w, s, rx0, rx1, ry0, ry1)
                        && edgeMayPass(e1.x, e1.y, e1.z, e1.w, s, rx0, rx1, ry0, ry1)
                        && edgeMayPass(e2.x, e2.y, e2.z, e2.w, s, rx0, rx1, ry0, ry1);
                }
            }
            const unsigned long long m = __ballot(keep);
            if (lane == 0) waveCnt[wv] = __popcll(m);
            __syncthreads();
            const int pre = __popcll(m & ((1ull << lane) - 1ull));
            int off = 0;
            #pragma unroll
            for (int w = 0; w < 4; ++w) if (w < wv) off += waveCnt[w];
            const int tot = waveCnt[0] + waveCnt[1] + waveCnt[2] + waveCnt[3];
            if (keep) list[listLen + off + pre] = (unsigned short)(t - chunkBase);
            __syncthreads();
            listLen += tot;
        }

        // ---- Phase B: 4-wide pipelined ordered scan, first hit wins ----
        if (listLen > 0) {
            const int last = listLen - 1;
            for (int i = 0; i < listLen; i += 4) {
                if (!__any(inb && !hit)) break;     // per-wave early exit
                const int c0 = list[i];
                const int c1 = list[min(i + 1, last)];
                const int c2 = list[min(i + 2, last)];
                const int c3 = list[min(i + 3, last)];
                const int t0 = __builtin_amdgcn_readfirstlane(chunkBase + c0);
                const int t1 = __builtin_amdgcn_readfirstlane(chunkBase + c1);
                const int t2 = __builtin_amdgcn_readfirstlane(chunkBase + c2);
                const int t3 = __builtin_amdgcn_readfirstlane(chunkBase + c3);
                const float4* R0 = (const float4*)(recs + 16 * t0);
                const float4* R1 = (const float4*)(recs + 16 * t1);
                const float4* R2 = (const float4*)(recs + 16 * t2);
                const float4* R3 = (const float4*)(recs + 16 * t3);
                // Issue all loads up front (one latency for 4 candidates).
                const float4 a00 = R0[0], a01 = R0[1], a02 = R0[2], a03 = R0[3];
                const float4 a10 = R1[0], a11 = R1[1], a12 = R1[2], a13 = R1[3];
                const float4 a20 = R2[0], a21 = R2[1], a22 = R2[2], a23 = R2[3];
                const float4 a30 = R3[0], a31 = R3[1], a32 = R3[2], a33 = R3[3];

                #define TESTC(q0, q1, q2, q3)                                           \
                    if (!hit) {                                                         \
                        const float w0 = q0.z * (py - q0.y) - q0.w * (px - q0.x);       \
                        const float w1 = q1.z * (py - q1.y) - q1.w * (px - q1.x);       \
                        const float w2 = q2.z * (py - q2.y) - q2.w * (px - q2.x);       \
                        const float iv = q3.x;                                          \
                        const float b0 = w0 * iv, b1 = w1 * iv, b2 = w2 * iv;           \
                        if ((b0 >= 0.f) & (b1 >= 0.f) & (b2 >= 0.f)) {                  \
                            hit = true; g0 = b0; g1 = b1; g2 = b2;                      \
                            j0 = __float_as_int(q3.y);                                  \
                            j1 = __float_as_int(q3.z);                                  \
                            j2 = __float_as_int(q3.w);                                  \
                        }                                                               \
                    }
                TESTC(a00, a01, a02, a03)
                TESTC(a10, a11, a12, a13)
                TESTC(a20, a21, a22, a23)
                TESTC(a30, a31, a32, a33)
                #undef TESTC
            }
        }
        if (__syncthreads_and(hit || !inb)) break;   // all resolved -> done
    }

    if (inb) {
        float o0 = 0.f, o1 = 0.f, o2 = 0.f;
        if (hit) {
            o0 = g0 * attr[3 * j0 + 0] + g1 * attr[3 * j1 + 0] + g2 * attr[3 * j2 + 0];
            o1 = g0 * attr[3 * j0 + 1] + g1 * attr[3 * j1 + 1] + g2 * attr[3 * j2 + 1];
            o2 = g0 * attr[3 * j0 + 2] + g1 * attr[3 * j1 + 2] + g2 * attr[3 * j2 + 2];
        }
        const int o = (pyi * res + pxi) * 3;
        out[o + 0] = o0; out[o + 1] = o1; out[o + 2] = o2;
    }
}

// ---- fallback (tiny workspace): proven-correct wave-per-pixel scan ----
__global__ __launch_bounds__(256) void bake_wave(
    const float* __restrict__ uv, const int* __restrict__ faces,
    const float* __restrict__ attr, float* __restrict__ out,
    int res, int nTri)
{
    const int lane = threadIdx.x & 63;
    const int wid  = blockIdx.x * (blockDim.x >> 6) + (threadIdx.x >> 6);
    const int npix = res * res;
    if (wid >= npix) return;
    const int pyi = wid / res, pxi = wid - pyi * res;
    const float rf = (float)res;
    const float px = ((float)pxi + 0.5f) / rf, py = ((float)pyi + 0.5f) / rf;
    for (int base = 0; base < nTri; base += 64) {
        const int t = base + lane;
        bool hit = false; float b0 = 0, b1 = 0, b2 = 0; int i0 = 0, i1 = 0, i2 = 0;
        if (t < nTri) {
            i0 = faces[3 * t]; i1 = faces[3 * t + 1]; i2 = faces[3 * t + 2];
            const float ax = uv[2 * i0], ay = uv[2 * i0 + 1];
            const float bx = uv[2 * i1], by = uv[2 * i1 + 1];
            const float cx = uv[2 * i2], cy = uv[2 * i2 + 1];
            const float area = (bx - ax) * (cy - ay) - (by - ay) * (cx - ax);
            if (fabsf(area) > 1e-9f) {
                const float inv = 1.0f / area;
                b0 = ((cx - bx) * (py - by) - (cy - by) * (px - bx)) * inv;
                b1 = ((ax - cx) * (py - cy) - (ay - cy) * (px - cx)) * inv;
                b2 = ((bx - ax) * (py - ay) - (by - ay) * (px - ax)) * inv;
                hit = (b0 >= 0.f) & (b1 >= 0.f) & (b2 >= 0.f);
            }
        }
        const unsigned long long m = __ballot(hit);
        if (m) {
            const int src = (int)__builtin_ctzll(m);
            b0 = __shfl(b0, src, 64); b1 = __shfl(b1, src, 64); b2 = __shfl(b2, src, 64);
            const int J0 = __shfl(i0, src, 64), J1 = __shfl(i1, src, 64), J2 = __shfl(i2, src, 64);
            if (lane == 0) {
                const int o = wid * 3;
                out[o + 0] = b0 * attr[3 * J0] + b1 * attr[3 * J1] + b2 * attr[3 * J2];
                out[o + 1] = b0 * attr[3 * J0 + 1] + b1 * attr[3 * J1 + 1] + b2 * attr[3 * J2 + 1];
                out[o + 2] = b0 * attr[3 * J0 + 2] + b1 * attr[3 * J1 + 2] + b2 * attr[3 * J2 + 2];
            }
            return;
        }
    }
    if (lane == 0) { const int o = wid * 3; out[o] = 0.f; out[o + 1] = 0.f; out[o + 2] = 0.f; }
}

extern "C" void kernel_launch(void* const* d_in, const int* in_sizes, int n_in,
                              void* d_out, int out_size, void* d_ws, size_t ws_size,
                              hipStream_t stream) {
    const float* attr  = (const float*)d_in[0];
    const float* uv    = (const float*)d_in[1];
    const int*   faces = (const int*)d_in[2];
    float*       out   = (float*)d_out;

    const int nTri = in_sizes[2] / 3;
    const int res  = (int)(sqrt((double)(out_size / 3)) + 0.5);
    const int npix = res * res;

    const size_t recsBytes = (size_t)nTri * 64;
    const size_t bboxBytes = (size_t)nTri * 16;

    if (ws_size >= recsBytes + bboxBytes) {
        float*  recs   = (float*)d_ws;
        float4* bboxes = (float4*)((char*)d_ws + recsBytes);
        prep<<<(nTri + 255) / 256, 256, 0, stream>>>(uv, faces, recs, bboxes, nTri);
        dim3 grid((res + TILE - 1) / TILE, (res + TILE - 1) / TILE);
        bake_tile<<<grid, 256, 0, stream>>>(recs, bboxes, attr, out, res, nTri);
    } else {
        bake_wave<<<(npix + 3) / 4, 256, 0, stream>>>(uv, faces, attr, out, res, nTri);
    }
}